// Round 3
// baseline (347.774 us; speedup 1.0000x reference)
//
#include <hip/hip_runtime.h>

typedef __attribute__((ext_vector_type(8))) short short8;
typedef __attribute__((ext_vector_type(4))) float floatx4;

__device__ __forceinline__ unsigned short f2b(float f) {
    union { float f; unsigned int i; } v; v.f = f;
    unsigned int u = v.i;
    u += 0x7FFFu + ((u >> 16) & 1u);   // round-nearest-even; NaN impossible here
    return (unsigned short)(u >> 16);
}

#define NTILES 2048   // 262144 rows / 128 rows-per-tile
#define GRID   1024   // persistent: each block handles 2 tiles, W staged once

// Block: 4 waves x 32 rows = 128 rows per tile.
// A = W (LDS), B = X  =>  C: col = x-row (lane-local), row = dout = n*16+q*4+r.
// Round-3 changes vs round-2 (evidence: WRITE_SIZE 294 MiB vs 128 ideal,
// FETCH 188.5 = 128 X + 60 W-storm, MfmaUtil 2%, 38% HBM):
//  - stores are PLAIN (nt caused partial-line write-through: 2.3x write amp)
//  - tile-0 X load/pack peeled ahead of W staging (overlap W miss storm)
//  - next-tile xfrag prefetched between MFMA and epilogue (xfrag dead there);
//    bias re-read from LDS per use to keep VGPR <= 128 (4 blocks/CU).
__global__ __launch_bounds__(256, 4) void mobius_linear_kernel(
    const float* __restrict__ X,
    const float* __restrict__ W,
    const float* __restrict__ Bias,
    float* __restrict__ Out)
{
    __shared__ unsigned short ldsW[128 * 136];
    __shared__ float ldsB[128];

    const int tid  = threadIdx.x;
    const int wave = tid >> 6;
    const int lane = tid & 63;
    const int q = lane >> 4;     // quad
    const int c = lane & 15;     // lane-local: x-row (B/C col) & W-row (A row)

    int t = blockIdx.x;
    short8 xfrag[2][4];
    float xn2[2];

    // load + pack one X tile into xfrag/xn2 (no LDS involved)
#define LOADX(T)                                                              \
    {                                                                         \
        const int rb_ = (T) * 128 + wave * 32;                                \
        xn2[0] = 0.f; xn2[1] = 0.f;                                           \
        _Pragma("unroll")                                                     \
        for (int g = 0; g < 2; ++g) {                                         \
            const float* xrow = X + (size_t)(rb_ + g * 16 + c) * 128;         \
            _Pragma("unroll")                                                 \
            for (int kc = 0; kc < 4; ++kc) {                                  \
                const floatx4* src =                                          \
                    reinterpret_cast<const floatx4*>(xrow + kc * 32 + q * 8); \
                floatx4 x0 = __builtin_nontemporal_load(src);                 \
                floatx4 x1 = __builtin_nontemporal_load(src + 1);             \
                short8 pk;                                                    \
                _Pragma("unroll")                                             \
                for (int j = 0; j < 4; ++j) {                                 \
                    xn2[g] = fmaf(x0[j], x0[j], xn2[g]);                      \
                    xn2[g] = fmaf(x1[j], x1[j], xn2[g]);                      \
                    pk[j] = (short)f2b(x0[j]);                                \
                    pk[4 + j] = (short)f2b(x1[j]);                            \
                }                                                             \
                xfrag[g][kc] = pk;                                            \
            }                                                                 \
        }                                                                     \
        xn2[0] += __shfl_xor(xn2[0], 16); xn2[0] += __shfl_xor(xn2[0], 32);   \
        xn2[1] += __shfl_xor(xn2[1], 16); xn2[1] += __shfl_xor(xn2[1], 32);   \
    }

    // ---- peel tile 0: X loads issued before (and overlapping) W staging ----
    LOADX(t);

    // ---- stage W into LDS as bf16 (once per block) ----
#pragma unroll
    for (int i = 0; i < 8; ++i) {
        int chunk = i * 256 + tid;          // 0..2047
        int row = chunk >> 4, cc = chunk & 15;
        const float* src = W + row * 128 + cc * 8;
        floatx4 w0 = *reinterpret_cast<const floatx4*>(src);
        floatx4 w1 = *reinterpret_cast<const floatx4*>(src + 4);
        short8 pk;
#pragma unroll
        for (int j = 0; j < 4; ++j) { pk[j] = (short)f2b(w0[j]); pk[4 + j] = (short)f2b(w1[j]); }
        *reinterpret_cast<short8*>(&ldsW[row * 136 + cc * 8]) = pk;
    }
    // ---- stage Bias into LDS (fp32, 512 B) ----
    if (tid < 32)
        *reinterpret_cast<floatx4*>(&ldsB[tid * 4]) =
            *reinterpret_cast<const floatx4*>(Bias + tid * 4);

    __syncthreads();   // the ONLY barrier: LDS is read-only from here on

    // ---- ||b||^2 ----
    float b2 = 0.f;
#pragma unroll
    for (int n = 0; n < 8; ++n) {
        floatx4 bv = *reinterpret_cast<const floatx4*>(&ldsB[n * 16 + q * 4]);
#pragma unroll
        for (int r = 0; r < 4; ++r) b2 = fmaf(bv[r], bv[r], b2);
    }
    b2 += __shfl_xor(b2, 16); b2 += __shfl_xor(b2, 32);

    for (;;) {
        // ---- MFMA: D[dout][xrow] ; A = W (LDS), B = X ----
        floatx4 acc[2][8];
#pragma unroll
        for (int g = 0; g < 2; ++g)
#pragma unroll
            for (int n = 0; n < 8; ++n)
                acc[g][n] = (floatx4){0.f, 0.f, 0.f, 0.f};

#pragma unroll
        for (int kc = 0; kc < 4; ++kc) {
#pragma unroll
            for (int n = 0; n < 8; ++n) {
                short8 wf = *reinterpret_cast<const short8*>(
                    &ldsW[(n * 16 + c) * 136 + kc * 32 + q * 8]);
                acc[0][n] = __builtin_amdgcn_mfma_f32_16x16x32_bf16(wf, xfrag[0][kc], acc[0][n], 0, 0, 0);
                acc[1][n] = __builtin_amdgcn_mfma_f32_16x16x32_bf16(wf, xfrag[1][kc], acc[1][n], 0, 0, 0);
            }
        }

        const int rowbase = t * 128 + wave * 32;
        const float cx0 = xn2[0], cx1 = xn2[1];   // keep current tile's row norms

        // ---- prefetch next tile's X (xfrag is dead after MFMA);
        //      HBM latency hides under the epilogue below ----
        const int tn = t + GRID;
        const bool more = (tn < NTILES);
        if (more) LOADX(tn);

        // ---- fused epilogue: lane owns x-row (rowbase + g*16 + c),
        //      douts {n*16 + q*4 + r}. Bias re-read from LDS (broadcast). ----
#pragma unroll
        for (int g = 0; g < 2; ++g) {
            float m2 = 0.f, mbv = 0.f;
#pragma unroll
            for (int n = 0; n < 8; ++n) {
                floatx4 bv = *reinterpret_cast<const floatx4*>(&ldsB[n * 16 + q * 4]);
#pragma unroll
                for (int r = 0; r < 4; ++r) {
                    float v = acc[g][n][r];
                    m2  = fmaf(v, v, m2);
                    mbv = fmaf(v, bv[r], mbv);
                }
            }
            // disjoint dout-sets across quads; sum over q
            m2  += __shfl_xor(m2, 16);  m2  += __shfl_xor(m2, 32);
            mbv += __shfl_xor(mbv, 16); mbv += __shfl_xor(mbv, 32);

            float xr2   = (g == 0) ? cx0 : cx1;
            float xnorm = fmaxf(sqrtf(xr2), 1e-15f);
            float u     = fminf(xnorm, 1.f - 1e-7f);
            float at    = 0.5f * __logf((1.f + u) / (1.f - u));   // artanh
            float Mxn   = fmaxf(sqrtf(m2), 1e-15f);
            float arg   = Mxn / xnorm * at;                        // >= 0
            float e     = __expf(2.f * arg);
            float th    = 1.f - 2.f / (e + 1.f);                   // tanh
            float scale = (Mxn <= 1e-10f) ? 0.f : th / Mxn;
            float y2 = scale * scale * m2;                         // ||y||^2
            float yb = scale * mbv;                                // y.b
            float t1  = 1.f + 2.f * yb + b2;
            float den = fmaxf(fmaf(y2, b2, 1.f + 2.f * yb), 1e-15f);
            float Af = t1 * scale / den;        // z = Af*Mx + Bf*bias
            float Bf = (1.f - y2) / den;
            float zn2 = Af * Af * m2 + 2.f * Af * Bf * mbv + Bf * Bf * b2;
            float zn  = fmaxf(sqrtf(zn2), 1e-15f);
            const float maxn = 1.f - 1e-5f;
            float fac = (zn > maxn) ? (maxn / zn) : 1.f;
            Af *= fac; Bf *= fac;

            float* orow = Out + (size_t)(rowbase + g * 16 + c) * 128;
#pragma unroll
            for (int n = 0; n < 8; ++n) {
                floatx4 bv = *reinterpret_cast<const floatx4*>(&ldsB[n * 16 + q * 4]);
                floatx4 o;
#pragma unroll
                for (int r = 0; r < 4; ++r)
                    o[r] = fmaf(Af, acc[g][n][r], Bf * bv[r]);
                *reinterpret_cast<floatx4*>(orow + n * 16 + q * 4) = o;   // plain store
            }
        }

        if (!more) break;
        t = tn;
    }
#undef LOADX
}

extern "C" void kernel_launch(void* const* d_in, const int* in_sizes, int n_in,
                              void* d_out, int out_size, void* d_ws, size_t ws_size,
                              hipStream_t stream) {
    const float* X    = (const float*)d_in[0];
    const float* W    = (const float*)d_in[1];
    const float* Bias = (const float*)d_in[2];
    float* Out = (float*)d_out;

    dim3 grid(GRID), block(256);
    hipLaunchKernelGGL(mobius_linear_kernel, grid, block, 0, stream, X, W, Bias, Out);
}

// Round 4
// 259.269 us; speedup vs baseline: 1.3414x; 1.3414x over previous
//
#include <hip/hip_runtime.h>

typedef __attribute__((ext_vector_type(8))) short short8;
typedef __attribute__((ext_vector_type(4))) float floatx4;

__device__ __forceinline__ unsigned short f2b(float f) {
    union { float f; unsigned int i; } v; v.f = f;
    unsigned int u = v.i;
    u += 0x7FFFu + ((u >> 16) & 1u);   // round-nearest-even; NaN impossible here
    return (unsigned short)(u >> 16);
}

#define NTILES 2048   // 262144 rows / 128 rows-per-tile
#define GRID   1024   // every block does exactly 2 tiles: bid and bid+1024

// Block: 4 waves x 32 rows = 128 rows per tile.
// A = W (LDS), B = X  =>  C: col = x-row (lane-local), row = dout = n*16+q*4+r.
// Round-4 changes (evidence: R3 VGPR=64 -> acc spilled to scratch, FETCH/WRITE
// inflated +120MB, dur 165->183; prefetch blocked behind `if(more)` branch):
//  - __launch_bounds__(256,3): register cap ~170, no spills (R2 compiled at 84)
//  - persistent loop fully unrolled into ONE basic block: MFMA(A), load(B),
//    epilogue(A), MFMA(B), epilogue(B) -> scheduler can overlap load(B) with
//    epilogue(A)'s VALU chain + stores
//  - W staging staggered by block parity to break the t=0 W miss-storm
//  - plain stores (nt write-through caused 2.3x write amp in R2)
__global__ __launch_bounds__(256, 3) void mobius_linear_kernel(
    const float* __restrict__ X,
    const float* __restrict__ W,
    const float* __restrict__ Bias,
    float* __restrict__ Out)
{
    __shared__ unsigned short ldsW[128 * 136];
    __shared__ float ldsB[128];

    const int tid  = threadIdx.x;
    const int wave = tid >> 6;
    const int lane = tid & 63;
    const int q = lane >> 4;     // quad
    const int c = lane & 15;     // lane-local: x-row (B/C col) & W-row (A row)

    // ---- load + pack one X tile (fp32 nt-loads, fp32 norms, bf16 pack) ----
    auto loadx = [&](int T, short8 (&xf)[2][4], float (&xn)[2]) {
        const int rb = T * 128 + wave * 32;
        xn[0] = 0.f; xn[1] = 0.f;
#pragma unroll
        for (int g = 0; g < 2; ++g) {
            const float* xrow = X + (size_t)(rb + g * 16 + c) * 128;
#pragma unroll
            for (int kc = 0; kc < 4; ++kc) {
                const floatx4* src = reinterpret_cast<const floatx4*>(xrow + kc * 32 + q * 8);
                floatx4 x0 = __builtin_nontemporal_load(src);
                floatx4 x1 = __builtin_nontemporal_load(src + 1);
                short8 pk;
#pragma unroll
                for (int j = 0; j < 4; ++j) {
                    xn[g] = fmaf(x0[j], x0[j], xn[g]);
                    xn[g] = fmaf(x1[j], x1[j], xn[g]);
                    pk[j] = (short)f2b(x0[j]); pk[4 + j] = (short)f2b(x1[j]);
                }
                xf[g][kc] = pk;
            }
        }
        // quads hold disjoint k-ranges of the same row; sum over q
        xn[0] += __shfl_xor(xn[0], 16); xn[0] += __shfl_xor(xn[0], 32);
        xn[1] += __shfl_xor(xn[1], 16); xn[1] += __shfl_xor(xn[1], 32);
    };

    // ---- stage W into LDS as bf16 (row stride 136 shorts = 272 B) ----
    auto stage_w = [&]() {
#pragma unroll
        for (int i = 0; i < 8; ++i) {
            int chunk = i * 256 + tid;          // 0..2047
            int row = chunk >> 4, cc = chunk & 15;
            const float* src = W + row * 128 + cc * 8;
            floatx4 w0 = *reinterpret_cast<const floatx4*>(src);
            floatx4 w1 = *reinterpret_cast<const floatx4*>(src + 4);
            short8 pk;
#pragma unroll
            for (int j = 0; j < 4; ++j) { pk[j] = (short)f2b(w0[j]); pk[4 + j] = (short)f2b(w1[j]); }
            *reinterpret_cast<short8*>(&ldsW[row * 136 + cc * 8]) = pk;
        }
    };

    short8 xfA[2][4], xfB[2][4];
    float xnA[2], xnB[2];
    const int t0 = blockIdx.x;
    const int t1 = blockIdx.x + GRID;

    // stagger: half the blocks stream X before touching W, so their W reads
    // arrive after the other half's L2 fills -> fewer HBM W misses
    if (blockIdx.x & 1) { loadx(t0, xfA, xnA); stage_w(); }
    else                { stage_w(); loadx(t0, xfA, xnA); }

    if (tid < 32)
        *reinterpret_cast<floatx4*>(&ldsB[tid * 4]) =
            *reinterpret_cast<const floatx4*>(Bias + tid * 4);

    __syncthreads();   // the ONLY barrier: LDS read-only from here on

    // ---- ||b||^2 ----
    float b2 = 0.f;
#pragma unroll
    for (int n = 0; n < 8; ++n) {
        floatx4 bv = *reinterpret_cast<const floatx4*>(&ldsB[n * 16 + q * 4]);
#pragma unroll
        for (int r = 0; r < 4; ++r) b2 = fmaf(bv[r], bv[r], b2);
    }
    b2 += __shfl_xor(b2, 16); b2 += __shfl_xor(b2, 32);

    floatx4 acc[2][8];

    auto mfma_all = [&](short8 (&xf)[2][4]) {
#pragma unroll
        for (int g = 0; g < 2; ++g)
#pragma unroll
            for (int n = 0; n < 8; ++n)
                acc[g][n] = (floatx4){0.f, 0.f, 0.f, 0.f};
#pragma unroll
        for (int kc = 0; kc < 4; ++kc) {
#pragma unroll
            for (int n = 0; n < 8; ++n) {
                short8 wf = *reinterpret_cast<const short8*>(
                    &ldsW[(n * 16 + c) * 136 + kc * 32 + q * 8]);
                acc[0][n] = __builtin_amdgcn_mfma_f32_16x16x32_bf16(wf, xf[0][kc], acc[0][n], 0, 0, 0);
                acc[1][n] = __builtin_amdgcn_mfma_f32_16x16x32_bf16(wf, xf[1][kc], acc[1][n], 0, 0, 0);
            }
        }
    };

    // lane owns x-row (rb + g*16 + c), douts {n*16 + q*4 + r}
    auto epilogue = [&](int T, float (&xn)[2]) {
        const int rb = T * 128 + wave * 32;
        floatx4 bfr[8];
#pragma unroll
        for (int n = 0; n < 8; ++n)
            bfr[n] = *reinterpret_cast<const floatx4*>(&ldsB[n * 16 + q * 4]);
#pragma unroll
        for (int g = 0; g < 2; ++g) {
            float m2 = 0.f, mbv = 0.f;
#pragma unroll
            for (int n = 0; n < 8; ++n)
#pragma unroll
                for (int r = 0; r < 4; ++r) {
                    float v = acc[g][n][r];
                    m2  = fmaf(v, v, m2);
                    mbv = fmaf(v, bfr[n][r], mbv);
                }
            // disjoint dout-sets across quads; sum over q
            m2  += __shfl_xor(m2, 16);  m2  += __shfl_xor(m2, 32);
            mbv += __shfl_xor(mbv, 16); mbv += __shfl_xor(mbv, 32);

            float xnorm = fmaxf(sqrtf(xn[g]), 1e-15f);
            float u     = fminf(xnorm, 1.f - 1e-7f);
            float at    = 0.5f * __logf((1.f + u) / (1.f - u));   // artanh
            float Mxn   = fmaxf(sqrtf(m2), 1e-15f);
            float arg   = Mxn / xnorm * at;                        // >= 0
            float e     = __expf(2.f * arg);
            float th    = 1.f - 2.f / (e + 1.f);                   // tanh
            float scale = (Mxn <= 1e-10f) ? 0.f : th / Mxn;
            float y2 = scale * scale * m2;                         // ||y||^2
            float yb = scale * mbv;                                // y.b
            float t1v = 1.f + 2.f * yb + b2;
            float den = fmaxf(fmaf(y2, b2, 1.f + 2.f * yb), 1e-15f);
            float Af = t1v * scale / den;        // z = Af*Mx + Bf*bias
            float Bf = (1.f - y2) / den;
            float zn2 = Af * Af * m2 + 2.f * Af * Bf * mbv + Bf * Bf * b2;
            float zn  = fmaxf(sqrtf(zn2), 1e-15f);
            const float maxn = 1.f - 1e-5f;
            float fac = (zn > maxn) ? (maxn / zn) : 1.f;
            Af *= fac; Bf *= fac;

            float* orow = Out + (size_t)(rb + g * 16 + c) * 128;
#pragma unroll
            for (int n = 0; n < 8; ++n) {
                floatx4 o;
#pragma unroll
                for (int r = 0; r < 4; ++r)
                    o[r] = fmaf(Af, acc[g][n][r], Bf * bfr[n][r]);
                *reinterpret_cast<floatx4*>(orow + n * 16 + q * 4) = o;   // plain store
            }
        }
    };

    // ---- straight-line 2-tile pipeline ----
    mfma_all(xfA);
    loadx(t1, xfB, xnB);       // in-flight while epilogue(A) runs
    epilogue(t0, xnA);
    mfma_all(xfB);
    epilogue(t1, xnB);
}

extern "C" void kernel_launch(void* const* d_in, const int* in_sizes, int n_in,
                              void* d_out, int out_size, void* d_ws, size_t ws_size,
                              hipStream_t stream) {
    const float* X    = (const float*)d_in[0];
    const float* W    = (const float*)d_in[1];
    const float* Bias = (const float*)d_in[2];
    float* Out = (float*)d_out;

    dim3 grid(GRID), block(256);
    hipLaunchKernelGGL(mobius_linear_kernel, grid, block, 0, stream, X, W, Bias, Out);
}